// Round 7
// baseline (359.227 us; speedup 1.0000x reference)
//
#include <hip/hip_runtime.h>

typedef short short8 __attribute__((ext_vector_type(8)));
typedef float floatx4 __attribute__((ext_vector_type(4)));
typedef unsigned short ushort_t;

// Problem constants: B=4, S=2048, D=768, H=12, Dh=64

__device__ inline ushort_t f2bf(float f) {
  union { float f; unsigned u; } x; x.f = f;
  unsigned u = x.u;
  unsigned r = u + 0x7fffu + ((u >> 16) & 1u);  // round-to-nearest-even
  return (ushort_t)(r >> 16);
}

// pack two floats to bf16x2 via v_perm (round-half-up; fine for p >= 0)
__device__ inline unsigned pk2(float a, float b) {
  union { float f; unsigned u; } x, y; x.f = a; y.f = b;
  return __builtin_amdgcn_perm(y.u + 0x8000u, x.u + 0x8000u, 0x07060302u);
}

__device__ inline float fexp2(float x) {
#if __has_builtin(__builtin_amdgcn_exp2f)
  return __builtin_amdgcn_exp2f(x);
#else
  return exp2f(x);
#endif
}

__device__ inline void async16(const void* g, void* l) {
  __builtin_amdgcn_global_load_lds((const __attribute__((address_space(1))) void*)g,
                                   (__attribute__((address_space(3))) void*)l,
                                   16, 0, 0);
}

// ---------------- fused input prep ----------------

__global__ __launch_bounds__(256) void conv_prep(
    const float* __restrict__ x, ushort_t* __restrict__ rx,
    const float* __restrict__ wq, const float* __restrict__ wk, const float* __restrict__ wv,
    const float* __restrict__ wo,
    const float* __restrict__ bq, const float* __restrict__ bk, const float* __restrict__ bv,
    ushort_t* __restrict__ wqkvT, ushort_t* __restrict__ woT, float* __restrict__ bqkv)
{
  __shared__ ushort_t t[64 * 72];
  const int tid = threadIdx.x;
  const int bid0 = blockIdx.x;
  if (bid0 < 6144) {
    int i = bid0 * 256 + tid;
    float4 f = ((const float4*)x)[i];
    ushort4 o;
    o.x = f2bf(f.x); o.y = f2bf(f.y); o.z = f2bf(f.z); o.w = f2bf(f.w);
    ((ushort4*)rx)[i] = o;
    return;
  }
  const int bid = bid0 - 6144;
  if (bid < 432) {
    int m = bid / 144, rem = bid % 144;
    int h = rem / 12, dt = rem % 12;
    int d0 = dt * 64;
    const float* w = (m == 0) ? wq : ((m == 1) ? wk : wv);
    const float* src = w + ((size_t)h * 768 + d0) * 64;
#pragma unroll
    for (int i = 0; i < 4; ++i) {
      int task = i * 256 + tid;
      int row = task >> 4, c4 = task & 15;
      float4 f = *(const float4*)(src + row * 64 + c4 * 4);
      ushort4 o4;
      o4.x = f2bf(f.x); o4.y = f2bf(f.y); o4.z = f2bf(f.z); o4.w = f2bf(f.w);
      *(ushort4*)&t[row * 72 + c4 * 4] = o4;
    }
    __syncthreads();
    ushort_t* dst = wqkvT + ((size_t)m * 768 + h * 64) * 768 + d0;
#pragma unroll
    for (int i = 0; i < 2; ++i) {
      int task = i * 256 + tid;
      int e = task >> 3, sc = task & 7;
      short8 d8;
#pragma unroll
      for (int j = 0; j < 8; ++j) d8[j] = (short)t[(sc * 8 + j) * 72 + e];
      *(short8*)(dst + (size_t)e * 768 + sc * 8) = d8;
    }
  } else if (bid < 576) {
    int b2 = bid - 432;
    int het = b2 / 12, dt = b2 % 12;
    int he0 = het * 64, d0 = dt * 64;
    const float* src = wo + (size_t)he0 * 768 + d0;
#pragma unroll
    for (int i = 0; i < 4; ++i) {
      int task = i * 256 + tid;
      int row = task >> 4, c4 = task & 15;
      float4 f = *(const float4*)(src + (size_t)row * 768 + c4 * 4);
      ushort4 o4;
      o4.x = f2bf(f.x); o4.y = f2bf(f.y); o4.z = f2bf(f.z); o4.w = f2bf(f.w);
      *(ushort4*)&t[row * 72 + c4 * 4] = o4;
    }
    __syncthreads();
    ushort_t* dst = woT + (size_t)d0 * 768 + he0;
#pragma unroll
    for (int i = 0; i < 2; ++i) {
      int task = i * 256 + tid;
      int dd = task >> 3, sc = task & 7;
      short8 d8;
#pragma unroll
      for (int j = 0; j < 8; ++j) d8[j] = (short)t[(sc * 8 + j) * 72 + dd];
      *(short8*)(dst + (size_t)dd * 768 + sc * 8) = d8;
    }
  } else {
    for (int idx = tid; idx < 2304; idx += 256) {
      int m = idx / 768, rem = idx - m * 768;
      const float* bp = (m == 0) ? bq : ((m == 1) ? bk : bv);
      bqkv[idx] = bp[rem];
    }
  }
}

// ---------------- QKV GEMM: 128x128, XCD-rect swizzle, 32KB LDS, 5 blk/CU ----------
// q/k col-tiles (col0<1536): SWAPPED mfma operands -> lane holds 4 consecutive
// cols at fixed row -> packed ushort4 stores. V col-tiles: normal orientation,
// LDS transpose in two 64-col half passes (reuses staging LDS).

__global__ __launch_bounds__(256, 5) void gemm_qkv(
    const ushort_t* __restrict__ A, const ushort_t* __restrict__ Bt,
    const float* __restrict__ bias,
    ushort_t* __restrict__ q, ushort_t* __restrict__ k, ushort_t* __restrict__ vt)
{
  __shared__ ushort_t sh[16384];  // A dbuf [0,8192), B dbuf [8192,16384); V-T half: 64x136
  const int tid = threadIdx.x;
  const int wave = tid >> 6, lane = tid & 63;
  const int ln15 = lane & 15, quad = lane >> 4;
  const int id = blockIdx.x;
  const int xk = id & 7, j = id >> 3;
  const int bx = (xk >> 1) * 16 + (j & 15);
  const int by = (xk & 1) * 9 + (j >> 4);
  const int row0 = bx * 128, col0 = by * 128;
  const int wm = (wave >> 1) * 64, wn = (wave & 1) * 64;
  const int c0 = wave * 2;
  const bool is_v = (col0 >= 1536);

  const ushort_t* gA0 = A + (size_t)(row0 + c0 * 16 + (lane >> 2)) * 768 + (lane & 3) * 8;
  const ushort_t* gB0 = Bt + (size_t)(col0 + c0 * 16 + (lane >> 2)) * 768 + (lane & 3) * 8;

  floatx4 acc[4][4];
#pragma unroll
  for (int mi = 0; mi < 4; ++mi)
#pragma unroll
    for (int ni = 0; ni < 4; ++ni)
      acc[mi][ni] = (floatx4){0.f, 0.f, 0.f, 0.f};

  async16(gA0, &sh[c0 * 512]);
  async16(gA0 + 16 * 768, &sh[c0 * 512 + 512]);
  async16(gB0, &sh[8192 + c0 * 512]);
  async16(gB0 + 16 * 768, &sh[8192 + c0 * 512 + 512]);
  __syncthreads();

  if (!is_v) {
    for (int kt = 0; kt < 24; ++kt) {
      const int buf = kt & 1;
      if (kt + 1 < 24) {
        ushort_t* dA = &sh[(buf ^ 1) * 4096];
        ushort_t* dB = &sh[8192 + (buf ^ 1) * 4096];
        async16(gA0 + (kt + 1) * 32, dA + c0 * 512);
        async16(gA0 + (kt + 1) * 32 + 16 * 768, dA + c0 * 512 + 512);
        async16(gB0 + (kt + 1) * 32, dB + c0 * 512);
        async16(gB0 + (kt + 1) * 32 + 16 * 768, dB + c0 * 512 + 512);
      }
      const ushort_t* sA = &sh[buf * 4096];
      const ushort_t* sB = &sh[8192 + buf * 4096];
      short8 af[4], bfv[4];
#pragma unroll
      for (int mi = 0; mi < 4; ++mi)
        af[mi] = *(const short8*)&sA[(wm + mi * 16 + ln15) * 32 + quad * 8];
#pragma unroll
      for (int ni = 0; ni < 4; ++ni)
        bfv[ni] = *(const short8*)&sB[(wn + ni * 16 + ln15) * 32 + quad * 8];
#pragma unroll
      for (int mi = 0; mi < 4; ++mi)
#pragma unroll
        for (int ni = 0; ni < 4; ++ni)  // SWAPPED: computes C^T fragment
          acc[mi][ni] = __builtin_amdgcn_mfma_f32_16x16x32_bf16(bfv[ni], af[mi], acc[mi][ni], 0, 0, 0);
      __syncthreads();
    }
    // epilogue: lane holds rows gr=...+ln15, cols gc0..gc0+3
    const float qscale = 0.125f * 1.44269504f;
#pragma unroll
    for (int mi = 0; mi < 4; ++mi) {
      int rr = row0 + wm + mi * 16 + ln15;
      int bb = rr >> 11, ss = rr & 2047;
#pragma unroll
      for (int ni = 0; ni < 4; ++ni) {
        int gc0 = col0 + wn + ni * 16 + quad * 4;
        int m = (gc0 >= 768) ? 1 : 0;
        int rem = gc0 - m * 768;
        int h = rem >> 6, e0 = rem & 63;
        float4 b4 = *(const float4*)&bias[gc0];
        float sc = m ? 1.f : qscale;
        ushort_t* dp = m ? k : q;
        ushort4 w4;
        w4.x = f2bf((acc[mi][ni][0] + b4.x) * sc);
        w4.y = f2bf((acc[mi][ni][1] + b4.y) * sc);
        w4.z = f2bf((acc[mi][ni][2] + b4.z) * sc);
        w4.w = f2bf((acc[mi][ni][3] + b4.w) * sc);
        *(ushort4*)(dp + (((size_t)(bb * 12 + h) * 2048 + ss) << 6) + e0) = w4;
      }
    }
  } else {
    for (int kt = 0; kt < 24; ++kt) {
      const int buf = kt & 1;
      if (kt + 1 < 24) {
        ushort_t* dA = &sh[(buf ^ 1) * 4096];
        ushort_t* dB = &sh[8192 + (buf ^ 1) * 4096];
        async16(gA0 + (kt + 1) * 32, dA + c0 * 512);
        async16(gA0 + (kt + 1) * 32 + 16 * 768, dA + c0 * 512 + 512);
        async16(gB0 + (kt + 1) * 32, dB + c0 * 512);
        async16(gB0 + (kt + 1) * 32 + 16 * 768, dB + c0 * 512 + 512);
      }
      const ushort_t* sA = &sh[buf * 4096];
      const ushort_t* sB = &sh[8192 + buf * 4096];
      short8 af[4], bfv[4];
#pragma unroll
      for (int mi = 0; mi < 4; ++mi)
        af[mi] = *(const short8*)&sA[(wm + mi * 16 + ln15) * 32 + quad * 8];
#pragma unroll
      for (int ni = 0; ni < 4; ++ni)
        bfv[ni] = *(const short8*)&sB[(wn + ni * 16 + ln15) * 32 + quad * 8];
#pragma unroll
      for (int mi = 0; mi < 4; ++mi)
#pragma unroll
        for (int ni = 0; ni < 4; ++ni)
          acc[mi][ni] = __builtin_amdgcn_mfma_f32_16x16x32_bf16(af[mi], bfv[ni], acc[mi][ni], 0, 0, 0);
      __syncthreads();
    }
    // V epilogue: two 64-col half passes through T[64][136] (col-major, both sides contiguous)
    const int relc0 = col0 - 1536;
    const int bb = row0 >> 11, s0 = row0 & 2047;
    const int myhalf = wn >> 6;  // wave-uniform
#pragma unroll
    for (int hf = 0; hf < 2; ++hf) {
      if (myhalf == hf) {
#pragma unroll
        for (int mi = 0; mi < 4; ++mi) {
#pragma unroll
          for (int ni = 0; ni < 4; ++ni) {
            int col = wn + ni * 16 + ln15;
            int rowb = wm + mi * 16 + quad * 4;
            float bia = bias[col0 + col];
            ushort4 w4;
            w4.x = f2bf(acc[mi][ni][0] + bia);
            w4.y = f2bf(acc[mi][ni][1] + bia);
            w4.z = f2bf(acc[mi][ni][2] + bia);
            w4.w = f2bf(acc[mi][ni][3] + bia);
            *(ushort4*)&sh[(col & 63) * 136 + rowb] = w4;
          }
        }
      }
      __syncthreads();
#pragma unroll
      for (int i = 0; i < 4; ++i) {
        int g = i * 256 + tid;          // 1024 tasks: lc(64) x chunk(16)
        int lc = g >> 4, chunk = g & 15;
        short8 d = *(const short8*)&sh[lc * 136 + chunk * 8];
        int c = hf * 64 + lc;
        int hh = (relc0 + c) >> 6, ee = (relc0 + c) & 63;
        *(short8*)(vt + (((size_t)(bb * 12 + hh) * 64 + ee) << 11) + s0 + chunk * 8) = d;
      }
      if (hf == 0) __syncthreads();  // reads done before half 1 overwrites T
    }
  }
}

// ---------------- out-proj GEMM: 64x128, swapped operands, float4 stores ----------

__global__ __launch_bounds__(256) void gemm_out(
    const ushort_t* __restrict__ A, const ushort_t* __restrict__ Bt,
    const float* __restrict__ bias, float* __restrict__ outf)
{
  __shared__ ushort_t lA[2][64 * 32];
  __shared__ ushort_t lB[2][128 * 32];
  const int tid = threadIdx.x;
  const int wave = tid >> 6, lane = tid & 63;
  const int ln15 = lane & 15, quad = lane >> 4;
  const int id = blockIdx.x;
  const int xk = id & 7, j = id >> 3;
  const int bx = xk * 16 + (j & 15);
  const int by = j >> 4;
  const int row0 = bx * 64, col0 = by * 128;
  const int wm = (wave >> 1) * 32, wn = (wave & 1) * 64;
  const int cb = wave * 2;

  const ushort_t* gA0 = A + (size_t)(row0 + wave * 16 + (lane >> 2)) * 768 + (lane & 3) * 8;
  const ushort_t* gB0 = Bt + (size_t)(col0 + cb * 16 + (lane >> 2)) * 768 + (lane & 3) * 8;

  floatx4 acc[2][4];
#pragma unroll
  for (int mi = 0; mi < 2; ++mi)
#pragma unroll
    for (int ni = 0; ni < 4; ++ni)
      acc[mi][ni] = (floatx4){0.f, 0.f, 0.f, 0.f};

  async16(gA0, &lA[0][wave * 512]);
  async16(gB0, &lB[0][cb * 512]);
  async16(gB0 + 16 * 768, &lB[0][cb * 512 + 512]);
  __syncthreads();

  for (int kt = 0; kt < 24; ++kt) {
    const int buf = kt & 1;
    if (kt + 1 < 24) {
      async16(gA0 + (kt + 1) * 32, &lA[buf ^ 1][wave * 512]);
      async16(gB0 + (kt + 1) * 32, &lB[buf ^ 1][cb * 512]);
      async16(gB0 + (kt + 1) * 32 + 16 * 768, &lB[buf ^ 1][cb * 512 + 512]);
    }
    short8 af[2], bfv[4];
#pragma unroll
    for (int mi = 0; mi < 2; ++mi)
      af[mi] = *(const short8*)&lA[buf][(wm + mi * 16 + ln15) * 32 + quad * 8];
#pragma unroll
    for (int ni = 0; ni < 4; ++ni)
      bfv[ni] = *(const short8*)&lB[buf][(wn + ni * 16 + ln15) * 32 + quad * 8];
#pragma unroll
    for (int mi = 0; mi < 2; ++mi)
#pragma unroll
      for (int ni = 0; ni < 4; ++ni)  // SWAPPED
        acc[mi][ni] = __builtin_amdgcn_mfma_f32_16x16x32_bf16(bfv[ni], af[mi], acc[mi][ni], 0, 0, 0);
    __syncthreads();
  }

#pragma unroll
  for (int mi = 0; mi < 2; ++mi) {
    int gr = row0 + wm + mi * 16 + ln15;
#pragma unroll
    for (int ni = 0; ni < 4; ++ni) {
      int gc0 = col0 + wn + ni * 16 + quad * 4;
      float4 b4 = *(const float4*)&bias[gc0];
      float4 w4;
      w4.x = acc[mi][ni][0] + b4.x;
      w4.y = acc[mi][ni][1] + b4.y;
      w4.z = acc[mi][ni][2] + b4.z;
      w4.w = acc[mi][ni][3] + b4.w;
      *(float4*)&outf[(size_t)gr * 768 + gc0] = w4;
    }
  }
}

// ---------------- flash attention (unchanged structure; perm pack + mask skip) ----

__device__ inline short8 frag_ld(const ushort_t* t, int row, int ch) {
  return *(const short8*)&t[row * 64 + (((ch ^ row) & 7) * 8)];
}

__global__ __launch_bounds__(256) void attn3(
    const ushort_t* __restrict__ Q, const ushort_t* __restrict__ K,
    const ushort_t* __restrict__ VT, ushort_t* __restrict__ Z)
{
  __shared__ ushort_t lK[2][64 * 64];
  __shared__ ushort_t lV[2][64 * 64];
  __shared__ ushort_t lPQ[128 * 64];
  const int tid = threadIdx.x;
  const int wave = tid >> 6, lane = tid & 63;
  const int ln15 = lane & 15, quad = lane >> 4;
  const int bi = blockIdx.x;
  const int bh = bi % 48;
  const int t = 15 - (bi / 48);
  const int h = bh % 12, b = bh / 12;
  const size_t base = (size_t)bh * 2048 * 64;
  const ushort_t* Qp = Q + base + (size_t)t * 128 * 64;
  const ushort_t* Kp = K + base;
  const ushort_t* Vp = VT + base;
  const int nk = 2 * t + 2;

  const int srow = tid >> 3, slch = tid & 7;
  const int sc_ = slch ^ (srow & 7);

#pragma unroll
  for (int i = 0; i < 4; ++i) {
    int task = i * 256 + tid;
    int row = task >> 3;
    int c = slch ^ (row & 7);
    async16(Qp + row * 64 + c * 8, &lPQ[task * 8]);
  }
  async16(Kp + (size_t)srow * 64 + sc_ * 8, &lK[0][tid * 8]);
  async16(Kp + (size_t)(srow + 32) * 64 + sc_ * 8, &lK[0][(256 + tid) * 8]);
  async16(Vp + (size_t)srow * 2048 + sc_ * 8, &lV[0][tid * 8]);
  async16(Vp + (size_t)(srow + 32) * 2048 + sc_ * 8, &lV[0][(256 + tid) * 8]);

  const ushort_t* kPre0 = Kp + (size_t)(64 + srow) * 64 + sc_ * 8;
  const ushort_t* kPre1 = kPre0 + 32 * 64;
  const ushort_t* vPre0 = Vp + (size_t)srow * 2048 + 64 + sc_ * 8;
  const ushort_t* vPre1 = vPre0 + 32 * 2048;

  __syncthreads();
  short8 qf[2][2];
#pragma unroll
  for (int c = 0; c < 2; ++c) {
    qf[c][0] = frag_ld(lPQ, wave * 32 + c * 16 + ln15, quad);
    qf[c][1] = frag_ld(lPQ, wave * 32 + c * 16 + ln15, quad + 4);
  }
  __syncthreads();

  float l_i[2] = {0.f, 0.f};
  floatx4 o[2][4];
#pragma unroll
  for (int c = 0; c < 2; ++c)
#pragma unroll
    for (int et = 0; et < 4; ++et) o[c][et] = (floatx4){0.f, 0.f, 0.f, 0.f};

  ushort_t* lPw = lPQ + wave * 2048;
  const int qg0 = t * 128 + wave * 32 + ln15;

  for (int kt = 0; kt < nk; ++kt) {
    const int buf = kt & 1;
    if (kt + 1 < nk) {
      ushort_t* dK = lK[buf ^ 1];
      ushort_t* dV = lV[buf ^ 1];
      async16(kPre0, dK + tid * 8);
      async16(kPre1, dK + (256 + tid) * 8);
      async16(vPre0, dV + tid * 8);
      async16(vPre1, dV + (256 + tid) * 8);
      kPre0 += 4096; kPre1 += 4096; vPre0 += 64; vPre1 += 64;
    }

    // last diagonal tile: waves 0,1 are fully masked -> skip all compute
    const bool skip = (kt == nk - 1) && (wave < 2);
    if (!skip) {
      floatx4 st[2][4];
#pragma unroll
      for (int ni = 0; ni < 4; ++ni) {
        short8 kf0 = frag_ld(lK[buf], ni * 16 + ln15, quad);
        short8 kf1 = frag_ld(lK[buf], ni * 16 + ln15, quad + 4);
#pragma unroll
        for (int c = 0; c < 2; ++c) {
          floatx4 z4 = (floatx4){0.f, 0.f, 0.f, 0.f};
          z4 = __builtin_amdgcn_mfma_f32_16x16x32_bf16(kf0, qf[c][0], z4, 0, 0, 0);
          st[c][ni] = __builtin_amdgcn_mfma_f32_16x16x32_bf16(kf1, qf[c][1], z4, 0, 0, 0);
        }
      }

      const bool masked = (kt >= 2 * t);
#pragma unroll
      for (int c = 0; c < 2; ++c) {
        const int qg = qg0 + c * 16;
        float p[16];
        float rs = 0.f;
#pragma unroll
        for (int ni = 0; ni < 4; ++ni)
#pragma unroll
          for (int r = 0; r < 4; ++r) {
            float x = st[c][ni][r];
            if (masked) {
              int kg = kt * 64 + ni * 16 + quad * 4 + r;
              x = (kg <= qg) ? x : -1e30f;
            }
            float pe = fexp2(x);
            p[ni * 4 + r] = pe;
            rs += pe;
          }
        rs += __shfl_xor(rs, 16);
        rs += __shfl_xor(rs, 32);
        l_i[c] += rs;
        const int rowl = c * 16 + ln15;
#pragma unroll
        for (int ni = 0; ni < 4; ++ni) {
          int chunk = 2 * ni + (quad >> 1);
          int pos = chunk ^ (rowl & 7);
          uint2 w;
          w.x = pk2(p[ni * 4 + 0], p[ni * 4 + 1]);
          w.y = pk2(p[ni * 4 + 2], p[ni * 4 + 3]);
          *(uint2*)&lPw[rowl * 64 + pos * 8 + (quad & 1) * 4] = w;
        }
      }

      short8 pf[2][2];
#pragma unroll
      for (int c = 0; c < 2; ++c) {
        pf[c][0] = frag_ld(lPw, c * 16 + ln15, quad);
        pf[c][1] = frag_ld(lPw, c * 16 + ln15, quad + 4);
      }
#pragma unroll
      for (int et = 0; et < 4; ++et) {
        short8 vf0 = frag_ld(lV[buf], et * 16 + ln15, quad);
        short8 vf1 = frag_ld(lV[buf], et * 16 + ln15, quad + 4);
#pragma unroll
        for (int c = 0; c < 2; ++c) {
          o[c][et] = __builtin_amdgcn_mfma_f32_16x16x32_bf16(vf0, pf[c][0], o[c][et], 0, 0, 0);
          o[c][et] = __builtin_amdgcn_mfma_f32_16x16x32_bf16(vf1, pf[c][1], o[c][et], 0, 0, 0);
        }
      }
    }
    __syncthreads();
  }

#pragma unroll
  for (int c = 0; c < 2; ++c) {
    float inv = 1.f / l_i[c];
    size_t zrow = (size_t)(b * 2048 + t * 128 + wave * 32 + c * 16 + ln15);
#pragma unroll
    for (int et = 0; et < 4; ++et) {
      ushort4 w;
      w.x = f2bf(o[c][et][0] * inv);
      w.y = f2bf(o[c][et][1] * inv);
      w.z = f2bf(o[c][et][2] * inv);
      w.w = f2bf(o[c][et][3] * inv);
      *(ushort4*)&Z[zrow * 768 + h * 64 + et * 16 + quad * 4] = w;
    }
  }
}

// ---------------- launch ----------------

extern "C" void kernel_launch(void* const* d_in, const int* in_sizes, int n_in,
                              void* d_out, int out_size, void* d_ws, size_t ws_size,
                              hipStream_t stream)
{
  const float* residual = (const float*)d_in[0];
  const float* W_Q = (const float*)d_in[1];
  const float* W_K = (const float*)d_in[2];
  const float* W_V = (const float*)d_in[3];
  const float* W_O = (const float*)d_in[4];
  const float* b_Q = (const float*)d_in[5];
  const float* b_K = (const float*)d_in[6];
  const float* b_V = (const float*)d_in[7];
  const float* b_O = (const float*)d_in[8];
  float* out = (float*)d_out;

  char* w = (char*)d_ws;
  ushort_t* rx    = (ushort_t*)(w + 0);          // [8192,768] bf16 (reused as z)
  ushort_t* wqkvT = (ushort_t*)(w + 12582912);   // [2304,768] bf16
  ushort_t* woT   = (ushort_t*)(w + 16121856);   // [768,768] bf16
  float*    bqkv  = (float*)   (w + 17301504);   // [2304] fp32
  ushort_t* q     = (ushort_t*)(w + 17310720);   // [B,H,S,64] bf16
  ushort_t* k     = (ushort_t*)(w + 29893632);
  ushort_t* vt    = (ushort_t*)(w + 55059456);   // [B,H,64,S] bf16
  ushort_t* z     = rx;                          // z overlays rx (rx dead after gemm_qkv)

  conv_prep<<<6721, 256, 0, stream>>>(residual, rx, W_Q, W_K, W_V, W_O,
                                      b_Q, b_K, b_V, wqkvT, woT, bqkv);
  gemm_qkv<<<1152, 256, 0, stream>>>(rx, wqkvT, bqkv, q, k, vt);
  attn3<<<768, 256, 0, stream>>>(q, k, vt, z);
  gemm_out<<<768, 256, 0, stream>>>(z, woT, b_O, out);
}

// Round 8
// 225.468 us; speedup vs baseline: 1.5932x; 1.5932x over previous
//
#include <hip/hip_runtime.h>

typedef short short8 __attribute__((ext_vector_type(8)));
typedef float floatx4 __attribute__((ext_vector_type(4)));
typedef unsigned short ushort_t;

// Problem constants: B=4, S=2048, D=768, H=12, Dh=64

__device__ inline ushort_t f2bf(float f) {
  union { float f; unsigned u; } x; x.f = f;
  unsigned u = x.u;
  unsigned r = u + 0x7fffu + ((u >> 16) & 1u);  // round-to-nearest-even
  return (ushort_t)(r >> 16);
}

// pack two floats to bf16x2 via v_perm (round-half-up; fine for p >= 0)
__device__ inline unsigned pk2(float a, float b) {
  union { float f; unsigned u; } x, y; x.f = a; y.f = b;
  return __builtin_amdgcn_perm(y.u + 0x8000u, x.u + 0x8000u, 0x07060302u);
}

__device__ inline float fexp2(float x) {
#if __has_builtin(__builtin_amdgcn_exp2f)
  return __builtin_amdgcn_exp2f(x);
#else
  return exp2f(x);
#endif
}

__device__ inline void async16(const void* g, void* l) {
  __builtin_amdgcn_global_load_lds((const __attribute__((address_space(1))) void*)g,
                                   (__attribute__((address_space(3))) void*)l,
                                   16, 0, 0);
}

// ---------------- fused input prep ----------------

__global__ __launch_bounds__(256) void conv_prep(
    const float* __restrict__ x, ushort_t* __restrict__ rx,
    const float* __restrict__ wq, const float* __restrict__ wk, const float* __restrict__ wv,
    const float* __restrict__ wo,
    const float* __restrict__ bq, const float* __restrict__ bk, const float* __restrict__ bv,
    ushort_t* __restrict__ wqkvT, ushort_t* __restrict__ woT, float* __restrict__ bqkv)
{
  __shared__ ushort_t t[64 * 72];
  const int tid = threadIdx.x;
  const int bid0 = blockIdx.x;
  if (bid0 < 6144) {
    int i = bid0 * 256 + tid;
    float4 f = ((const float4*)x)[i];
    ushort4 o;
    o.x = f2bf(f.x); o.y = f2bf(f.y); o.z = f2bf(f.z); o.w = f2bf(f.w);
    ((ushort4*)rx)[i] = o;
    return;
  }
  const int bid = bid0 - 6144;
  if (bid < 432) {
    int m = bid / 144, rem = bid % 144;
    int h = rem / 12, dt = rem % 12;
    int d0 = dt * 64;
    const float* w = (m == 0) ? wq : ((m == 1) ? wk : wv);
    const float* src = w + ((size_t)h * 768 + d0) * 64;
#pragma unroll
    for (int i = 0; i < 4; ++i) {
      int task = i * 256 + tid;
      int row = task >> 4, c4 = task & 15;
      float4 f = *(const float4*)(src + row * 64 + c4 * 4);
      ushort4 o4;
      o4.x = f2bf(f.x); o4.y = f2bf(f.y); o4.z = f2bf(f.z); o4.w = f2bf(f.w);
      *(ushort4*)&t[row * 72 + c4 * 4] = o4;
    }
    __syncthreads();
    ushort_t* dst = wqkvT + ((size_t)m * 768 + h * 64) * 768 + d0;
#pragma unroll
    for (int i = 0; i < 2; ++i) {
      int task = i * 256 + tid;
      int e = task >> 3, sc = task & 7;
      short8 d8;
#pragma unroll
      for (int j = 0; j < 8; ++j) d8[j] = (short)t[(sc * 8 + j) * 72 + e];
      *(short8*)(dst + (size_t)e * 768 + sc * 8) = d8;
    }
  } else if (bid < 576) {
    int b2 = bid - 432;
    int het = b2 / 12, dt = b2 % 12;
    int he0 = het * 64, d0 = dt * 64;
    const float* src = wo + (size_t)he0 * 768 + d0;
#pragma unroll
    for (int i = 0; i < 4; ++i) {
      int task = i * 256 + tid;
      int row = task >> 4, c4 = task & 15;
      float4 f = *(const float4*)(src + (size_t)row * 768 + c4 * 4);
      ushort4 o4;
      o4.x = f2bf(f.x); o4.y = f2bf(f.y); o4.z = f2bf(f.z); o4.w = f2bf(f.w);
      *(ushort4*)&t[row * 72 + c4 * 4] = o4;
    }
    __syncthreads();
    ushort_t* dst = woT + (size_t)d0 * 768 + he0;
#pragma unroll
    for (int i = 0; i < 2; ++i) {
      int task = i * 256 + tid;
      int dd = task >> 3, sc = task & 7;
      short8 d8;
#pragma unroll
      for (int j = 0; j < 8; ++j) d8[j] = (short)t[(sc * 8 + j) * 72 + dd];
      *(short8*)(dst + (size_t)dd * 768 + sc * 8) = d8;
    }
  } else {
    for (int idx = tid; idx < 2304; idx += 256) {
      int m = idx / 768, rem = idx - m * 768;
      const float* bp = (m == 0) ? bq : ((m == 1) ? bk : bv);
      bqkv[idx] = bp[rem];
    }
  }
}

// ---------------- QKV GEMM: 128x128, XCD-rect swizzle, 32KB LDS ----------
// NOTE: plain __launch_bounds__(256). Round 7's (256,5) forced VGPR=48 ->
// accumulator spilled to scratch (WRITE_SIZE 36->350 MB, 2.8x slower).
// Natural allocation (~92 VGPR) + 32KB LDS already reaches 5 blocks/CU.
// q/k col-tiles: SWAPPED mfma operands -> packed ushort4 stores.
// V col-tiles: normal orientation, LDS transpose in two 64-col half passes.

__global__ __launch_bounds__(256) void gemm_qkv(
    const ushort_t* __restrict__ A, const ushort_t* __restrict__ Bt,
    const float* __restrict__ bias,
    ushort_t* __restrict__ q, ushort_t* __restrict__ k, ushort_t* __restrict__ vt)
{
  __shared__ ushort_t sh[16384];  // A dbuf [0,8192), B dbuf [8192,16384); V-T half: 64x136
  const int tid = threadIdx.x;
  const int wave = tid >> 6, lane = tid & 63;
  const int ln15 = lane & 15, quad = lane >> 4;
  const int id = blockIdx.x;
  const int xk = id & 7, j = id >> 3;
  const int bx = (xk >> 1) * 16 + (j & 15);
  const int by = (xk & 1) * 9 + (j >> 4);
  const int row0 = bx * 128, col0 = by * 128;
  const int wm = (wave >> 1) * 64, wn = (wave & 1) * 64;
  const int c0 = wave * 2;
  const bool is_v = (col0 >= 1536);

  const ushort_t* gA0 = A + (size_t)(row0 + c0 * 16 + (lane >> 2)) * 768 + (lane & 3) * 8;
  const ushort_t* gB0 = Bt + (size_t)(col0 + c0 * 16 + (lane >> 2)) * 768 + (lane & 3) * 8;

  floatx4 acc[4][4];
#pragma unroll
  for (int mi = 0; mi < 4; ++mi)
#pragma unroll
    for (int ni = 0; ni < 4; ++ni)
      acc[mi][ni] = (floatx4){0.f, 0.f, 0.f, 0.f};

  async16(gA0, &sh[c0 * 512]);
  async16(gA0 + 16 * 768, &sh[c0 * 512 + 512]);
  async16(gB0, &sh[8192 + c0 * 512]);
  async16(gB0 + 16 * 768, &sh[8192 + c0 * 512 + 512]);
  __syncthreads();

  if (!is_v) {
    for (int kt = 0; kt < 24; ++kt) {
      const int buf = kt & 1;
      if (kt + 1 < 24) {
        ushort_t* dA = &sh[(buf ^ 1) * 4096];
        ushort_t* dB = &sh[8192 + (buf ^ 1) * 4096];
        async16(gA0 + (kt + 1) * 32, dA + c0 * 512);
        async16(gA0 + (kt + 1) * 32 + 16 * 768, dA + c0 * 512 + 512);
        async16(gB0 + (kt + 1) * 32, dB + c0 * 512);
        async16(gB0 + (kt + 1) * 32 + 16 * 768, dB + c0 * 512 + 512);
      }
      const ushort_t* sA = &sh[buf * 4096];
      const ushort_t* sB = &sh[8192 + buf * 4096];
      short8 af[4], bfv[4];
#pragma unroll
      for (int mi = 0; mi < 4; ++mi)
        af[mi] = *(const short8*)&sA[(wm + mi * 16 + ln15) * 32 + quad * 8];
#pragma unroll
      for (int ni = 0; ni < 4; ++ni)
        bfv[ni] = *(const short8*)&sB[(wn + ni * 16 + ln15) * 32 + quad * 8];
#pragma unroll
      for (int mi = 0; mi < 4; ++mi)
#pragma unroll
        for (int ni = 0; ni < 4; ++ni)  // SWAPPED: computes C^T fragment
          acc[mi][ni] = __builtin_amdgcn_mfma_f32_16x16x32_bf16(bfv[ni], af[mi], acc[mi][ni], 0, 0, 0);
      __syncthreads();
    }
    // epilogue: lane holds row gr, cols gc0..gc0+3 -> packed ushort4 stores
    const float qscale = 0.125f * 1.44269504f;
#pragma unroll
    for (int mi = 0; mi < 4; ++mi) {
      int rr = row0 + wm + mi * 16 + ln15;
      int bb = rr >> 11, ss = rr & 2047;
#pragma unroll
      for (int ni = 0; ni < 4; ++ni) {
        int gc0 = col0 + wn + ni * 16 + quad * 4;
        int m = (gc0 >= 768) ? 1 : 0;
        int rem = gc0 - m * 768;
        int h = rem >> 6, e0 = rem & 63;
        float4 b4 = *(const float4*)&bias[gc0];
        float sc = m ? 1.f : qscale;
        ushort_t* dp = m ? k : q;
        ushort4 w4;
        w4.x = f2bf((acc[mi][ni][0] + b4.x) * sc);
        w4.y = f2bf((acc[mi][ni][1] + b4.y) * sc);
        w4.z = f2bf((acc[mi][ni][2] + b4.z) * sc);
        w4.w = f2bf((acc[mi][ni][3] + b4.w) * sc);
        *(ushort4*)(dp + (((size_t)(bb * 12 + h) * 2048 + ss) << 6) + e0) = w4;
      }
    }
  } else {
    for (int kt = 0; kt < 24; ++kt) {
      const int buf = kt & 1;
      if (kt + 1 < 24) {
        ushort_t* dA = &sh[(buf ^ 1) * 4096];
        ushort_t* dB = &sh[8192 + (buf ^ 1) * 4096];
        async16(gA0 + (kt + 1) * 32, dA + c0 * 512);
        async16(gA0 + (kt + 1) * 32 + 16 * 768, dA + c0 * 512 + 512);
        async16(gB0 + (kt + 1) * 32, dB + c0 * 512);
        async16(gB0 + (kt + 1) * 32 + 16 * 768, dB + c0 * 512 + 512);
      }
      const ushort_t* sA = &sh[buf * 4096];
      const ushort_t* sB = &sh[8192 + buf * 4096];
      short8 af[4], bfv[4];
#pragma unroll
      for (int mi = 0; mi < 4; ++mi)
        af[mi] = *(const short8*)&sA[(wm + mi * 16 + ln15) * 32 + quad * 8];
#pragma unroll
      for (int ni = 0; ni < 4; ++ni)
        bfv[ni] = *(const short8*)&sB[(wn + ni * 16 + ln15) * 32 + quad * 8];
#pragma unroll
      for (int mi = 0; mi < 4; ++mi)
#pragma unroll
        for (int ni = 0; ni < 4; ++ni)
          acc[mi][ni] = __builtin_amdgcn_mfma_f32_16x16x32_bf16(af[mi], bfv[ni], acc[mi][ni], 0, 0, 0);
      __syncthreads();
    }
    // V epilogue: two 64-col half passes through T[64][136]
    const int relc0 = col0 - 1536;
    const int bb = row0 >> 11, s0 = row0 & 2047;
    const int myhalf = wn >> 6;  // wave-uniform
#pragma unroll
    for (int hf = 0; hf < 2; ++hf) {
      if (myhalf == hf) {
#pragma unroll
        for (int mi = 0; mi < 4; ++mi) {
#pragma unroll
          for (int ni = 0; ni < 4; ++ni) {
            int col = wn + ni * 16 + ln15;
            int rowb = wm + mi * 16 + quad * 4;
            float bia = bias[col0 + col];
            ushort4 w4;
            w4.x = f2bf(acc[mi][ni][0] + bia);
            w4.y = f2bf(acc[mi][ni][1] + bia);
            w4.z = f2bf(acc[mi][ni][2] + bia);
            w4.w = f2bf(acc[mi][ni][3] + bia);
            *(ushort4*)&sh[(col & 63) * 136 + rowb] = w4;
          }
        }
      }
      __syncthreads();
#pragma unroll
      for (int i = 0; i < 4; ++i) {
        int g = i * 256 + tid;          // 1024 tasks: lc(64) x chunk(16)
        int lc = g >> 4, chunk = g & 15;
        short8 d = *(const short8*)&sh[lc * 136 + chunk * 8];
        int c = hf * 64 + lc;
        int hh = (relc0 + c) >> 6, ee = (relc0 + c) & 63;
        *(short8*)(vt + (((size_t)(bb * 12 + hh) * 64 + ee) << 11) + s0 + chunk * 8) = d;
      }
      if (hf == 0) __syncthreads();  // reads done before half 1 overwrites T
    }
  }
}

// ---------------- out-proj GEMM: 64x128, swapped operands, float4 stores ----------

__global__ __launch_bounds__(256) void gemm_out(
    const ushort_t* __restrict__ A, const ushort_t* __restrict__ Bt,
    const float* __restrict__ bias, float* __restrict__ outf)
{
  __shared__ ushort_t lA[2][64 * 32];
  __shared__ ushort_t lB[2][128 * 32];
  const int tid = threadIdx.x;
  const int wave = tid >> 6, lane = tid & 63;
  const int ln15 = lane & 15, quad = lane >> 4;
  const int id = blockIdx.x;
  const int xk = id & 7, j = id >> 3;
  const int bx = xk * 16 + (j & 15);
  const int by = j >> 4;
  const int row0 = bx * 64, col0 = by * 128;
  const int wm = (wave >> 1) * 32, wn = (wave & 1) * 64;
  const int cb = wave * 2;

  const ushort_t* gA0 = A + (size_t)(row0 + wave * 16 + (lane >> 2)) * 768 + (lane & 3) * 8;
  const ushort_t* gB0 = Bt + (size_t)(col0 + cb * 16 + (lane >> 2)) * 768 + (lane & 3) * 8;

  floatx4 acc[2][4];
#pragma unroll
  for (int mi = 0; mi < 2; ++mi)
#pragma unroll
    for (int ni = 0; ni < 4; ++ni)
      acc[mi][ni] = (floatx4){0.f, 0.f, 0.f, 0.f};

  async16(gA0, &lA[0][wave * 512]);
  async16(gB0, &lB[0][cb * 512]);
  async16(gB0 + 16 * 768, &lB[0][cb * 512 + 512]);
  __syncthreads();

  for (int kt = 0; kt < 24; ++kt) {
    const int buf = kt & 1;
    if (kt + 1 < 24) {
      async16(gA0 + (kt + 1) * 32, &lA[buf ^ 1][wave * 512]);
      async16(gB0 + (kt + 1) * 32, &lB[buf ^ 1][cb * 512]);
      async16(gB0 + (kt + 1) * 32 + 16 * 768, &lB[buf ^ 1][cb * 512 + 512]);
    }
    short8 af[2], bfv[4];
#pragma unroll
    for (int mi = 0; mi < 2; ++mi)
      af[mi] = *(const short8*)&lA[buf][(wm + mi * 16 + ln15) * 32 + quad * 8];
#pragma unroll
    for (int ni = 0; ni < 4; ++ni)
      bfv[ni] = *(const short8*)&lB[buf][(wn + ni * 16 + ln15) * 32 + quad * 8];
#pragma unroll
    for (int mi = 0; mi < 2; ++mi)
#pragma unroll
      for (int ni = 0; ni < 4; ++ni)  // SWAPPED
        acc[mi][ni] = __builtin_amdgcn_mfma_f32_16x16x32_bf16(bfv[ni], af[mi], acc[mi][ni], 0, 0, 0);
    __syncthreads();
  }

#pragma unroll
  for (int mi = 0; mi < 2; ++mi) {
    int gr = row0 + wm + mi * 16 + ln15;
#pragma unroll
    for (int ni = 0; ni < 4; ++ni) {
      int gc0 = col0 + wn + ni * 16 + quad * 4;
      float4 b4 = *(const float4*)&bias[gc0];
      float4 w4;
      w4.x = acc[mi][ni][0] + b4.x;
      w4.y = acc[mi][ni][1] + b4.y;
      w4.z = acc[mi][ni][2] + b4.z;
      w4.w = acc[mi][ni][3] + b4.w;
      *(float4*)&outf[(size_t)gr * 768 + gc0] = w4;
    }
  }
}

// ---------------- flash attention (perm pack + mask skip) ----------------

__device__ inline short8 frag_ld(const ushort_t* t, int row, int ch) {
  return *(const short8*)&t[row * 64 + (((ch ^ row) & 7) * 8)];
}

__global__ __launch_bounds__(256) void attn3(
    const ushort_t* __restrict__ Q, const ushort_t* __restrict__ K,
    const ushort_t* __restrict__ VT, ushort_t* __restrict__ Z)
{
  __shared__ ushort_t lK[2][64 * 64];
  __shared__ ushort_t lV[2][64 * 64];
  __shared__ ushort_t lPQ[128 * 64];
  const int tid = threadIdx.x;
  const int wave = tid >> 6, lane = tid & 63;
  const int ln15 = lane & 15, quad = lane >> 4;
  const int bi = blockIdx.x;
  const int bh = bi % 48;
  const int t = 15 - (bi / 48);
  const int h = bh % 12, b = bh / 12;
  const size_t base = (size_t)bh * 2048 * 64;
  const ushort_t* Qp = Q + base + (size_t)t * 128 * 64;
  const ushort_t* Kp = K + base;
  const ushort_t* Vp = VT + base;
  const int nk = 2 * t + 2;

  const int srow = tid >> 3, slch = tid & 7;
  const int sc_ = slch ^ (srow & 7);

#pragma unroll
  for (int i = 0; i < 4; ++i) {
    int task = i * 256 + tid;
    int row = task >> 3;
    int c = slch ^ (row & 7);
    async16(Qp + row * 64 + c * 8, &lPQ[task * 8]);
  }
  async16(Kp + (size_t)srow * 64 + sc_ * 8, &lK[0][tid * 8]);
  async16(Kp + (size_t)(srow + 32) * 64 + sc_ * 8, &lK[0][(256 + tid) * 8]);
  async16(Vp + (size_t)srow * 2048 + sc_ * 8, &lV[0][tid * 8]);
  async16(Vp + (size_t)(srow + 32) * 2048 + sc_ * 8, &lV[0][(256 + tid) * 8]);

  const ushort_t* kPre0 = Kp + (size_t)(64 + srow) * 64 + sc_ * 8;
  const ushort_t* kPre1 = kPre0 + 32 * 64;
  const ushort_t* vPre0 = Vp + (size_t)srow * 2048 + 64 + sc_ * 8;
  const ushort_t* vPre1 = vPre0 + 32 * 2048;

  __syncthreads();
  short8 qf[2][2];
#pragma unroll
  for (int c = 0; c < 2; ++c) {
    qf[c][0] = frag_ld(lPQ, wave * 32 + c * 16 + ln15, quad);
    qf[c][1] = frag_ld(lPQ, wave * 32 + c * 16 + ln15, quad + 4);
  }
  __syncthreads();

  float l_i[2] = {0.f, 0.f};
  floatx4 o[2][4];
#pragma unroll
  for (int c = 0; c < 2; ++c)
#pragma unroll
    for (int et = 0; et < 4; ++et) o[c][et] = (floatx4){0.f, 0.f, 0.f, 0.f};

  ushort_t* lPw = lPQ + wave * 2048;
  const int qg0 = t * 128 + wave * 32 + ln15;

  for (int kt = 0; kt < nk; ++kt) {
    const int buf = kt & 1;
    if (kt + 1 < nk) {
      ushort_t* dK = lK[buf ^ 1];
      ushort_t* dV = lV[buf ^ 1];
      async16(kPre0, dK + tid * 8);
      async16(kPre1, dK + (256 + tid) * 8);
      async16(vPre0, dV + tid * 8);
      async16(vPre1, dV + (256 + tid) * 8);
      kPre0 += 4096; kPre1 += 4096; vPre0 += 64; vPre1 += 64;
    }

    const bool skip = (kt == nk - 1) && (wave < 2);
    if (!skip) {
      floatx4 st[2][4];
#pragma unroll
      for (int ni = 0; ni < 4; ++ni) {
        short8 kf0 = frag_ld(lK[buf], ni * 16 + ln15, quad);
        short8 kf1 = frag_ld(lK[buf], ni * 16 + ln15, quad + 4);
#pragma unroll
        for (int c = 0; c < 2; ++c) {
          floatx4 z4 = (floatx4){0.f, 0.f, 0.f, 0.f};
          z4 = __builtin_amdgcn_mfma_f32_16x16x32_bf16(kf0, qf[c][0], z4, 0, 0, 0);
          st[c][ni] = __builtin_amdgcn_mfma_f32_16x16x32_bf16(kf1, qf[c][1], z4, 0, 0, 0);
        }
      }

      const bool masked = (kt >= 2 * t);
#pragma unroll
      for (int c = 0; c < 2; ++c) {
        const int qg = qg0 + c * 16;
        float p[16];
        float rs = 0.f;
#pragma unroll
        for (int ni = 0; ni < 4; ++ni)
#pragma unroll
          for (int r = 0; r < 4; ++r) {
            float x = st[c][ni][r];
            if (masked) {
              int kg = kt * 64 + ni * 16 + quad * 4 + r;
              x = (kg <= qg) ? x : -1e30f;
            }
            float pe = fexp2(x);
            p[ni * 4 + r] = pe;
            rs += pe;
          }
        rs += __shfl_xor(rs, 16);
        rs += __shfl_xor(rs, 32);
        l_i[c] += rs;
        const int rowl = c * 16 + ln15;
#pragma unroll
        for (int ni = 0; ni < 4; ++ni) {
          int chunk = 2 * ni + (quad >> 1);
          int pos = chunk ^ (rowl & 7);
          uint2 w;
          w.x = pk2(p[ni * 4 + 0], p[ni * 4 + 1]);
          w.y = pk2(p[ni * 4 + 2], p[ni * 4 + 3]);
          *(uint2*)&lPw[rowl * 64 + pos * 8 + (quad & 1) * 4] = w;
        }
      }

      short8 pf[2][2];
#pragma unroll
      for (int c = 0; c < 2; ++c) {
        pf[c][0] = frag_ld(lPw, c * 16 + ln15, quad);
        pf[c][1] = frag_ld(lPw, c * 16 + ln15, quad + 4);
      }
#pragma unroll
      for (int et = 0; et < 4; ++et) {
        short8 vf0 = frag_ld(lV[buf], et * 16 + ln15, quad);
        short8 vf1 = frag_ld(lV[buf], et * 16 + ln15, quad + 4);
#pragma unroll
        for (int c = 0; c < 2; ++c) {
          o[c][et] = __builtin_amdgcn_mfma_f32_16x16x32_bf16(vf0, pf[c][0], o[c][et], 0, 0, 0);
          o[c][et] = __builtin_amdgcn_mfma_f32_16x16x32_bf16(vf1, pf[c][1], o[c][et], 0, 0, 0);
        }
      }
    }
    __syncthreads();
  }

#pragma unroll
  for (int c = 0; c < 2; ++c) {
    float inv = 1.f / l_i[c];
    size_t zrow = (size_t)(b * 2048 + t * 128 + wave * 32 + c * 16 + ln15);
#pragma unroll
    for (int et = 0; et < 4; ++et) {
      ushort4 w;
      w.x = f2bf(o[c][et][0] * inv);
      w.y = f2bf(o[c][et][1] * inv);
      w.z = f2bf(o[c][et][2] * inv);
      w.w = f2bf(o[c][et][3] * inv);
      *(ushort4*)&Z[zrow * 768 + h * 64 + et * 16 + quad * 4] = w;
    }
  }
}

// ---------------- launch ----------------

extern "C" void kernel_launch(void* const* d_in, const int* in_sizes, int n_in,
                              void* d_out, int out_size, void* d_ws, size_t ws_size,
                              hipStream_t stream)
{
  const float* residual = (const float*)d_in[0];
  const float* W_Q = (const float*)d_in[1];
  const float* W_K = (const float*)d_in[2];
  const float* W_V = (const float*)d_in[3];
  const float* W_O = (const float*)d_in[4];
  const float* b_Q = (const float*)d_in[5];
  const float* b_K = (const float*)d_in[6];
  const float* b_V = (const float*)d_in[7];
  const float* b_O = (const float*)d_in[8];
  float* out = (float*)d_out;

  char* w = (char*)d_ws;
  ushort_t* rx    = (ushort_t*)(w + 0);          // [8192,768] bf16 (reused as z)
  ushort_t* wqkvT = (ushort_t*)(w + 12582912);   // [2304,768] bf16
  ushort_t* woT   = (ushort_t*)(w + 16121856);   // [768,768] bf16
  float*    bqkv  = (float*)   (w + 17301504);   // [2304] fp32
  ushort_t* q     = (ushort_t*)(w + 17310720);   // [B,H,S,64] bf16
  ushort_t* k     = (ushort_t*)(w + 29893632);
  ushort_t* vt    = (ushort_t*)(w + 55059456);   // [B,H,64,S] bf16
  ushort_t* z     = rx;                          // z overlays rx (rx dead after gemm_qkv)

  conv_prep<<<6721, 256, 0, stream>>>(residual, rx, W_Q, W_K, W_V, W_O,
                                      b_Q, b_K, b_V, wqkvT, woT, bqkv);
  gemm_qkv<<<1152, 256, 0, stream>>>(rx, wqkvT, bqkv, q, k, vt);
  attn3<<<768, 256, 0, stream>>>(q, k, vt, z);
  gemm_out<<<768, 256, 0, stream>>>(z, woT, b_O, out);
}